// Round 11
// baseline (483.672 us; speedup 1.0000x reference)
//
#include <hip/hip_runtime.h>

#define EPS_ 1e-8f

// sizes: B=16, N=2048, D=128, NS=8, H=128, steps=4
constexpr int OFF_K     = 0;                       // 16*2048*128 = 4194304
constexpr int OFF_WQT   = 4194304;                 // 16384
constexpr int OFF_WKT   = OFF_WQT  + 16384;
constexpr int OFF_WIHT  = OFF_WKT  + 16384;        // 49152
constexpr int OFF_WHHT  = OFF_WIHT + 49152;        // 49152
constexpr int OFF_WM1T  = OFF_WHHT + 49152;        // 16384
constexpr int OFF_WM2T  = OFF_WM1T + 16384;        // 16384
constexpr int OFF_WO1T  = OFF_WM2T + 16384;        // 65536
constexpr int OFF_WO2T  = OFF_WO1T + 65536;        // 32768
constexpr int OFF_SLOTS = OFF_WO2T + 32768;        // 32768
constexpr int OFF_PI    = OFF_SLOTS+ 32768;        // 128
constexpr int OFF_MUS   = OFF_PI   + 128;          // 16384
constexpr int OFF_WA    = OFF_MUS  + 16384;        // 16384 (iv)
constexpr int OFF_WB    = OFF_WA   + 16384;        // 16384 (-2*q*iv)
constexpr int OFF_UN    = OFF_WB   + 16384;        // 16*32*8*128 = 524288
constexpr int OFF_S2    = OFF_UN   + 524288;       // 524288
constexpr int OFF_DEN   = OFF_S2   + 524288;       // 16*32*8 = 4096
constexpr int OFF_CZ    = OFF_DEN  + 4096;         // 128
constexpr int OFF_CNT   = OFF_CZ   + 128;          // 64 ints (step x b counters)

struct Args {
  const float *xin, *noise, *smu, *sls, *Wq, *Wk, *Wih, *Whh, *bih, *bhh,
              *Wm1, *bm1, *Wm2, *bm2, *gin, *bin, *gsl, *bsl, *gmu, *bmu,
              *Wo1, *bo1, *Wo2, *bo2;
  float* ws;
  float* out;
};

// ---------------------------------------------------------------------------
__global__ __launch_bounds__(256) void init_kernel(
    const float* __restrict__ Wq,  const float* __restrict__ Wk,
    const float* __restrict__ Wih, const float* __restrict__ Whh,
    const float* __restrict__ Wm1, const float* __restrict__ Wm2,
    const float* __restrict__ Wo1, const float* __restrict__ Wo2,
    const float* __restrict__ smu, const float* __restrict__ sls,
    const float* __restrict__ noise, float* __restrict__ ws) {
  int idx = blockIdx.x * 256 + threadIdx.x;
  if (idx < 16384) { int j = idx >> 7, d = idx & 127; ws[OFF_WQT + d*128 + j] = Wq[idx]; return; }
  idx -= 16384;
  if (idx < 16384) { int j = idx >> 7, d = idx & 127; ws[OFF_WKT + d*128 + j] = Wk[idx]; return; }
  idx -= 16384;
  if (idx < 49152) { int j = idx >> 7, d = idx & 127; ws[OFF_WIHT + d*384 + j] = Wih[idx]; return; }
  idx -= 49152;
  if (idx < 49152) { int j = idx >> 7, d = idx & 127; ws[OFF_WHHT + d*384 + j] = Whh[idx]; return; }
  idx -= 49152;
  if (idx < 16384) { int j = idx >> 7, d = idx & 127; ws[OFF_WM1T + d*128 + j] = Wm1[idx]; return; }
  idx -= 16384;
  if (idx < 16384) { int j = idx >> 7, d = idx & 127; ws[OFF_WM2T + d*128 + j] = Wm2[idx]; return; }
  idx -= 16384;
  if (idx < 65536) { int j = idx >> 8, d = idx & 255; ws[OFF_WO1T + d*256 + j] = Wo1[idx]; return; }
  idx -= 65536;
  if (idx < 32768) { int j = idx >> 8, m = idx & 255; ws[OFF_WO2T + m*128 + j] = Wo2[idx]; return; }
  idx -= 32768;
  if (idx < 32768) { int c = idx & 255; ws[OFF_SLOTS + idx] = smu[c] + expf(sls[c]) * noise[idx]; return; }
  idx -= 32768;
  if (idx < 128) { ws[OFF_PI + idx] = 0.125f; return; }
  idx -= 128;
  if (idx < 64) { ((int*)(ws + OFF_CNT))[idx] = 0; }
}

// ---------------------------------------------------------------------------
// Merged k + s1 dispatch (round-10, unchanged): blocks [0,512) -> k tile,
// blocks [512,640) -> initial s1.
__global__ __launch_bounds__(256) void ks1_kernel(
    const float* __restrict__ xin, const float* __restrict__ g, const float* __restrict__ bb,
    const float* __restrict__ WkT, float* __restrict__ kout,
    const float* __restrict__ slots, const float* __restrict__ gsl, const float* __restrict__ bsl,
    const float* __restrict__ WqT, float* __restrict__ mus,
    float* __restrict__ wA, float* __restrict__ wB, float* __restrict__ cz) {
  __shared__ float xsT[128][72];
  __shared__ float2 red2[64][4];
  __shared__ float mrow[64], srow[64];
  int t = threadIdx.x;
  if (blockIdx.x < 512) {
    long long base = (long long)blockIdx.x * 64 * 128;
    int r = t >> 2, q = t & 3;
    float vals[32];
    {
      const float4* src = (const float4*)(xin + base + r * 128 + q * 32);
      #pragma unroll
      for (int i = 0; i < 8; ++i) *(float4*)&vals[i * 4] = src[i];
    }
    {
      float s = 0.f, ss = 0.f;
      #pragma unroll
      for (int i = 0; i < 32; ++i) { float v = vals[i]; s += v; ss = fmaf(v, v, ss); }
      red2[r][q] = make_float2(s, ss);
    }
    __syncthreads();
    if (t < 64) {
      float s = 0.f, ss = 0.f;
      #pragma unroll
      for (int c = 0; c < 4; ++c) { float2 p = red2[t][c]; s += p.x; ss += p.y; }
      float m = s * (1.0f / 128.0f);
      float var = ss * (1.0f / 128.0f) - m * m;
      mrow[t] = m; srow[t] = rsqrtf(var + 1e-5f);
    }
    __syncthreads();
    {
      float m = mrow[r], is = srow[r];
      #pragma unroll 8
      for (int u = 0; u < 32; ++u) {
        int d = q * 32 + u;
        xsT[d][r] = (vals[u] - m) * is * g[d] + bb[d];
      }
    }
    __syncthreads();
    int j4 = t & 31, rg = t >> 5;
    int r0 = rg * 8;
    float a0[8], a1[8], a2[8], a3[8];
    #pragma unroll
    for (int i = 0; i < 8; ++i) { a0[i] = 0.f; a1[i] = 0.f; a2[i] = 0.f; a3[i] = 0.f; }
    #pragma unroll 2
    for (int d = 0; d < 128; ++d) {
      float4 wv = *(const float4*)(WkT + d * 128 + j4 * 4);
      float4 x0 = *(const float4*)&xsT[d][r0];
      float4 x1 = *(const float4*)&xsT[d][r0 + 4];
      a0[0] = fmaf(x0.x, wv.x, a0[0]); a1[0] = fmaf(x0.x, wv.y, a1[0]);
      a2[0] = fmaf(x0.x, wv.z, a2[0]); a3[0] = fmaf(x0.x, wv.w, a3[0]);
      a0[1] = fmaf(x0.y, wv.x, a0[1]); a1[1] = fmaf(x0.y, wv.y, a1[1]);
      a2[1] = fmaf(x0.y, wv.z, a2[1]); a3[1] = fmaf(x0.y, wv.w, a3[1]);
      a0[2] = fmaf(x0.z, wv.x, a0[2]); a1[2] = fmaf(x0.z, wv.y, a1[2]);
      a2[2] = fmaf(x0.z, wv.z, a2[2]); a3[2] = fmaf(x0.z, wv.w, a3[2]);
      a0[3] = fmaf(x0.w, wv.x, a0[3]); a1[3] = fmaf(x0.w, wv.y, a1[3]);
      a2[3] = fmaf(x0.w, wv.z, a2[3]); a3[3] = fmaf(x0.w, wv.w, a3[3]);
      a0[4] = fmaf(x1.x, wv.x, a0[4]); a1[4] = fmaf(x1.x, wv.y, a1[4]);
      a2[4] = fmaf(x1.x, wv.z, a2[4]); a3[4] = fmaf(x1.x, wv.w, a3[4]);
      a0[5] = fmaf(x1.y, wv.x, a0[5]); a1[5] = fmaf(x1.y, wv.y, a1[5]);
      a2[5] = fmaf(x1.y, wv.z, a2[5]); a3[5] = fmaf(x1.y, wv.w, a3[5]);
      a0[6] = fmaf(x1.z, wv.x, a0[6]); a1[6] = fmaf(x1.z, wv.y, a1[6]);
      a2[6] = fmaf(x1.z, wv.z, a2[6]); a3[6] = fmaf(x1.z, wv.w, a3[6]);
      a0[7] = fmaf(x1.w, wv.x, a0[7]); a1[7] = fmaf(x1.w, wv.y, a1[7]);
      a2[7] = fmaf(x1.w, wv.z, a2[7]); a3[7] = fmaf(x1.w, wv.w, a3[7]);
    }
    #pragma unroll
    for (int i = 0; i < 8; ++i) {
      float* o = kout + base + (long long)(r0 + i) * 128 + j4 * 4;
      *(float4*)o = make_float4(a0[i], a1[i], a2[i], a3[i]);
    }
  } else {
    int bi = blockIdx.x - 512;
    float* f = &xsT[0][0];
    float* sl    = f;
    float* qs_l  = f + 256;
    float* ivs_l = f + 384;
    float2* wr   = (float2*)(f + 512);
    float* wrC   = f + 520;
    float v = slots[bi * 256 + t];
    float s = v, ss = v * v;
    #pragma unroll
    for (int o = 32; o > 0; o >>= 1) { s += __shfl_down(s, o); ss += __shfl_down(ss, o); }
    if ((t & 63) == 0) wr[t >> 6] = make_float2(s, ss);
    __syncthreads();
    float fs  = wr[0].x + wr[1].x + wr[2].x + wr[3].x;
    float fss = wr[0].y + wr[1].y + wr[2].y + wr[3].y;
    float m   = fs * (1.0f/256.0f);
    float var = fss * (1.0f/256.0f) - m * m;
    float isr = rsqrtf(var + 1e-5f);
    float sn  = (v - m) * isr * gsl[t] + bsl[t];
    sl[t] = sn;
    __syncthreads();
    if (t < 128) {
      float acc = 0.f;
      #pragma unroll 4
      for (int d = 0; d < 128; ++d) acc = fmaf(sl[d], WqT[d * 128 + t], acc);
      qs_l[t] = acc;
      mus[bi * 128 + t] = sn;
    } else {
      int jj = t - 128;
      float acc = 0.f;
      #pragma unroll 4
      for (int d = 0; d < 128; ++d) acc = fmaf(sl[128 + d], WqT[d * 128 + jj], acc);
      ivs_l[jj] = expf(-2.0f * acc);
    }
    __syncthreads();
    float cp = 0.f;
    if (t < 128) {
      float iv = ivs_l[t], q = qs_l[t];
      wA[bi * 128 + t] = iv;
      wB[bi * 128 + t] = -2.0f * q * iv;
      cp = q * q * iv;
    }
    #pragma unroll
    for (int o = 32; o > 0; o >>= 1) cp += __shfl_down(cp, o);
    if ((t & 63) == 0) wrC[t >> 6] = cp;
    __syncthreads();
    if (t == 0) cz[bi] = wrC[0] + wrC[1];
  }
}

// ---------------------------------------------------------------------------
// Fused step kernel: s2 (dots -> gamma -> partials) + last-block-per-b s3
// (reduce + GRU + LN + MLP + upd_ls + next-s1 or final out MLP).
struct ScrS3 {
  float xs[8][128];
  float hs[8][128];
  float gh[2][8][128];   // [0]=grus, [1]=hl ; later overlaid as sln/hh [8][256]
  float m1s[8][128];
  float uarr[8][256];
  float2 wr2[8][2];
  float wrC[8][2];
};
union UScr {
  struct { float pdots[16][64][8]; } p1;              // 32KB
  struct { float pP[2][4][8][128]; } p2;              // 16KB
  ScrS3 s3;                                           // ~28.4KB
};

__global__ __launch_bounds__(1024) void step_kernel(Args a, int step) {
  float* ws = a.ws;
  const float* kmat = ws + OFF_K;
  float* wA  = ws + OFF_WA;  float* wB  = ws + OFF_WB;
  float* czp = ws + OFF_CZ;  float* pip = ws + OFF_PI;
  float* wun = ws + OFF_UN;  float* ws2 = ws + OFF_S2;
  float* wden= ws + OFF_DEN; float* mus = ws + OFF_MUS;
  const float* WihT = ws + OFF_WIHT; const float* WhhT = ws + OFF_WHHT;
  const float* Wm1T = ws + OFF_WM1T; const float* Wm2T = ws + OFF_WM2T;
  const float* WqT  = ws + OFF_WQT;
  const float* Wo1T = ws + OFF_WO1T; const float* Wo2T = ws + OFF_WO2T;
  float* slots = ws + OFF_SLOTS;

  __shared__ UScr u;
  __shared__ float es[64][9];
  __shared__ float recip[64];
  __shared__ float gT[8][72];
  __shared__ float pd[8][8];
  __shared__ float pisl[8], czl[8];
  __shared__ int sflag;
  int t = threadIdx.x;
  int chunk = blockIdx.x, b = blockIdx.y;
  if (t < 8) { pisl[t] = pip[b * 8 + t]; czl[t] = czp[b * 8 + t]; }
  // ---- phase 1 (t<512): thread (w = t&15, nt = t>>4 -> rows 2nt, 2nt+1)
  if (t < 512) {
    int w = t & 15, nt = t >> 4;
    int n0 = nt * 2;
    const float4* kr4 = (const float4*)(kmat + (long long)(b * 2048 + chunk * 64) * 128);
    const float4* wa4 = (const float4*)(wA + b * 1024);
    const float4* wb4 = (const float4*)(wB + b * 1024);
    float acc0[8] = {0,0,0,0,0,0,0,0};
    float acc1[8] = {0,0,0,0,0,0,0,0};
    #pragma unroll
    for (int i = 0; i < 2; ++i) {
      int gg = i * 16 + w;
      float4 k0 = kr4[n0 * 32 + gg];
      float4 k1 = kr4[(n0 + 1) * 32 + gg];
      float x0 = k0.x * k0.x, y0 = k0.y * k0.y, z0 = k0.z * k0.z, w0 = k0.w * k0.w;
      float x1 = k1.x * k1.x, y1 = k1.y * k1.y, z1 = k1.z * k1.z, w1 = k1.w * k1.w;
      #pragma unroll
      for (int s = 0; s < 8; ++s) {
        float4 a4 = wa4[s * 32 + gg];
        float4 b4 = wb4[s * 32 + gg];
        float c0 = acc0[s], c1 = acc1[s];
        c0 = fmaf(x0, a4.x, c0); c0 = fmaf(k0.x, b4.x, c0);
        c0 = fmaf(y0, a4.y, c0); c0 = fmaf(k0.y, b4.y, c0);
        c0 = fmaf(z0, a4.z, c0); c0 = fmaf(k0.z, b4.z, c0);
        c0 = fmaf(w0, a4.w, c0); c0 = fmaf(k0.w, b4.w, c0);
        c1 = fmaf(x1, a4.x, c1); c1 = fmaf(k1.x, b4.x, c1);
        c1 = fmaf(y1, a4.y, c1); c1 = fmaf(k1.y, b4.y, c1);
        c1 = fmaf(z1, a4.z, c1); c1 = fmaf(k1.z, b4.z, c1);
        c1 = fmaf(w1, a4.w, c1); c1 = fmaf(k1.w, b4.w, c1);
        acc0[s] = c0; acc1[s] = c1;
      }
    }
    *(float4*)&u.p1.pdots[w][n0][0]     = make_float4(acc0[0], acc0[1], acc0[2], acc0[3]);
    *(float4*)&u.p1.pdots[w][n0][4]     = make_float4(acc0[4], acc0[5], acc0[6], acc0[7]);
    *(float4*)&u.p1.pdots[w][n0 + 1][0] = make_float4(acc1[0], acc1[1], acc1[2], acc1[3]);
    *(float4*)&u.p1.pdots[w][n0 + 1][4] = make_float4(acc1[4], acc1[5], acc1[6], acc1[7]);
  }
  __syncthreads();
  float e = 0.f;
  if (t < 512) {
    int n2 = t >> 3, s = t & 7;
    float dots = czl[s];
    #pragma unroll
    for (int w = 0; w < 16; ++w) dots += u.p1.pdots[w][n2][s];
    e = (expf(-dots) + EPS_) * pisl[s];
    es[n2][s] = e;
  }
  __syncthreads();
  if (t < 64) {
    float ssum = 0.f;
    #pragma unroll
    for (int s = 0; s < 8; ++s) ssum += es[t][s];
    recip[t] = 1.0f / ssum;
  }
  __syncthreads();
  if (t < 512) {
    int n2 = t >> 3, s = t & 7;
    float gam = e * recip[n2];
    gT[s][n2] = gam;
    float p = gam;
    p += __shfl_down(p, 8); p += __shfl_down(p, 16); p += __shfl_down(p, 32);
    if ((t & 63) < 8) pd[t >> 6][t & 7] = p;
  }
  __syncthreads();
  if (t < 8) {
    float sden = 0.f;
    #pragma unroll
    for (int w = 0; w < 8; ++w) sden += pd[w][t];
    wden[(b * 32 + chunk) * 8 + t] = sden;
  }
  // ---- phase 2: thread (g = t&31 d-granule, sl = (t>>5)&7, nh = t>>8)
  {
    int g = t & 31, sl = (t >> 5) & 7, nh = t >> 8;
    const float4* kr4 = (const float4*)(kmat + (long long)(b * 2048 + chunk * 64) * 128);
    float4 ua = {0, 0, 0, 0}, qa = {0, 0, 0, 0};
    #pragma unroll 2
    for (int n = nh * 16; n < nh * 16 + 16; ++n) {
      float4 kv = kr4[n * 32 + g];
      float gam = gT[sl][n];
      ua.x = fmaf(gam, kv.x, ua.x); qa.x = fmaf(gam, kv.x * kv.x, qa.x);
      ua.y = fmaf(gam, kv.y, ua.y); qa.y = fmaf(gam, kv.y * kv.y, qa.y);
      ua.z = fmaf(gam, kv.z, ua.z); qa.z = fmaf(gam, kv.z * kv.z, qa.z);
      ua.w = fmaf(gam, kv.w, ua.w); qa.w = fmaf(gam, kv.w * kv.w, qa.w);
    }
    *(float4*)&u.p2.pP[0][nh][sl][g * 4] = ua;
    *(float4*)&u.p2.pP[1][nh][sl][g * 4] = qa;
  }
  __syncthreads();
  {
    int uq = t >> 9, rem = t & 511;
    int sl = rem >> 6, d0 = (rem & 63) * 2;
    float* dst = (uq == 0 ? wun : ws2);
    long long pbase = (long long)((b * 32 + chunk) * 8 + sl) * 128;
    #pragma unroll
    for (int eo = 0; eo < 2; ++eo) {
      int d = d0 + eo;
      dst[pbase + d] = u.p2.pP[uq][0][sl][d] + u.p2.pP[uq][1][sl][d] +
                       u.p2.pP[uq][2][sl][d] + u.p2.pP[uq][3][sl][d];
    }
  }
  __syncthreads();
  // ---- completion signal (device-scope)
  if (t == 0) {
    __threadfence();  // release: flush this XCD's L2 (block's stores completed at barrier)
    sflag = atomicAdd((int*)(ws + OFF_CNT) + step * 16 + b, 1);
  }
  __syncthreads();
  if (sflag != 31) return;
  __threadfence();    // acquire: invalidate caches before reading remote partials
  // ================= s3 for batch b (8 slots x 128 threads) =================
  ScrS3* p = &u.s3;
  int i = t >> 7, d = t & 127, bi = b * 8 + i;
  float un = 0.f, s2v = 0.f, den = 0.f;
  for (int c = 0; c < 32; ++c) {
    long long po = (long long)((b * 32 + c) * 8 + i) * 128 + d;
    un += wun[po]; s2v += ws2[po];
  }
  for (int c = 0; c < 32; ++c) den += wden[(b * 32 + c) * 8 + i];
  p->xs[i][d] = un / den;
  p->hs[i][d] = mus[bi * 128 + d];
  __syncthreads();
  float a0 = 0, a1 = 0, a2 = 0, a3 = 0, a4 = 0, a5 = 0;
  #pragma unroll 2
  for (int dd = 0; dd < 128; ++dd) {
    float xv = p->xs[i][dd], hv = p->hs[i][dd];
    const float* wi = &WihT[dd * 384 + d];
    const float* wh = &WhhT[dd * 384 + d];
    a0 = fmaf(xv, wi[0],   a0);
    a1 = fmaf(xv, wi[128], a1);
    a2 = fmaf(xv, wi[256], a2);
    a3 = fmaf(hv, wh[0],   a3);
    a4 = fmaf(hv, wh[128], a4);
    a5 = fmaf(hv, wh[256], a5);
  }
  float ir = a0 + a.bih[d], iz = a1 + a.bih[128 + d], inn = a2 + a.bih[256 + d];
  float hr = a3 + a.bhh[d], hz = a4 + a.bhh[128 + d], hn  = a5 + a.bhh[256 + d];
  float rg = 1.0f / (1.0f + expf(-(ir + hr)));
  float zg = 1.0f / (1.0f + expf(-(iz + hz)));
  float nn = tanhf(inn + rg * hn);
  float gru = (1.0f - zg) * nn + zg * p->hs[i][d];
  p->gh[0][i][d] = gru;
  {
    float s = gru, ssq = gru * gru;
    #pragma unroll
    for (int o = 32; o > 0; o >>= 1) { s += __shfl_down(s, o); ssq += __shfl_down(ssq, o); }
    if ((d & 63) == 0) p->wr2[i][d >> 6] = make_float2(s, ssq);
  }
  __syncthreads();
  {
    float fs = p->wr2[i][0].x + p->wr2[i][1].x;
    float fss = p->wr2[i][0].y + p->wr2[i][1].y;
    float mean = fs * (1.0f / 128.0f);
    float var  = fss * (1.0f / 128.0f) - mean * mean;
    p->gh[1][i][d] = (gru - mean) * rsqrtf(var + 1e-5f) * a.gmu[d] + a.bmu[d];
  }
  __syncthreads();
  {
    float m1 = 0.f;
    #pragma unroll 4
    for (int dd = 0; dd < 128; ++dd)
      m1 = fmaf(p->gh[1][i][dd], Wm1T[dd * 128 + d], m1);
    p->m1s[i][d] = fmaxf(m1 + a.bm1[d], 0.f);
  }
  __syncthreads();
  float uu, lsv;
  {
    float m2 = 0.f;
    #pragma unroll 4
    for (int dd = 0; dd < 128; ++dd)
      m2 = fmaf(p->m1s[i][dd], Wm2T[dd * 128 + d], m2);
    uu = gru + m2 + a.bm2[d];
    float val = (s2v - 2.0f * uu * un + uu * uu * den) / den;
    lsv = 0.5f * logf(fmaxf(val, 0.0f) + EPS_);
  }
  __syncthreads();   // gh region about to be overlaid; ensure m1/m2 reads done
  slots[bi * 256 + d]       = uu;
  slots[bi * 256 + 128 + d] = lsv;
  p->uarr[i][d] = uu; p->uarr[i][128 + d] = lsv;
  if (d == 0) pip[bi] = den;
  __syncthreads();
  float* ov = &p->gh[0][0][0];   // 2048-float overlay region (sln / hh)
  if (step < 3) {
    // ---- fused next-iter s1: LN over 256 + q/ivar + wA/wB/cz
    float v0 = p->uarr[i][d], v1 = p->uarr[i][128 + d];
    {
      float s = v0 + v1, ssq = v0 * v0 + v1 * v1;
      #pragma unroll
      for (int o = 32; o > 0; o >>= 1) { s += __shfl_down(s, o); ssq += __shfl_down(ssq, o); }
      if ((d & 63) == 0) p->wr2[i][d >> 6] = make_float2(s, ssq);
    }
    __syncthreads();
    float* sln = ov + i * 256;
    {
      float fs = p->wr2[i][0].x + p->wr2[i][1].x;
      float fss = p->wr2[i][0].y + p->wr2[i][1].y;
      float m = fs * (1.0f / 256.0f);
      float var = fss * (1.0f / 256.0f) - m * m;
      float isr = rsqrtf(var + 1e-5f);
      sln[d]       = (v0 - m) * isr * a.gsl[d] + a.bsl[d];
      sln[128 + d] = (v1 - m) * isr * a.gsl[128 + d] + a.bsl[128 + d];
    }
    __syncthreads();
    float qacc = 0.f, iacc = 0.f;
    #pragma unroll 4
    for (int dd = 0; dd < 128; ++dd) {
      float wv = WqT[dd * 128 + d];
      qacc = fmaf(sln[dd],       wv, qacc);
      iacc = fmaf(sln[128 + dd], wv, iacc);
    }
    float iv = expf(-2.0f * iacc);
    wA[bi * 128 + d] = iv;
    wB[bi * 128 + d] = -2.0f * qacc * iv;
    mus[bi * 128 + d] = sln[d];
    float cp = qacc * qacc * iv;
    #pragma unroll
    for (int o = 32; o > 0; o >>= 1) cp += __shfl_down(cp, o);
    if ((d & 63) == 0) p->wrC[i][d >> 6] = cp;
    __syncthreads();
    if (d == 0) czp[bi] = p->wrC[i][0] + p->wrC[i][1];
  } else {
    // ---- final output MLP
    float* hh = ov + i * 256;
    float acc0 = 0.f, acc1 = 0.f;
    #pragma unroll 4
    for (int dd = 0; dd < 256; ++dd) {
      float uv = p->uarr[i][dd];
      acc0 = fmaf(uv, Wo1T[dd * 256 + d],       acc0);
      acc1 = fmaf(uv, Wo1T[dd * 256 + 128 + d], acc1);
    }
    hh[d]       = fmaxf(acc0 + a.bo1[d], 0.f);
    hh[128 + d] = fmaxf(acc1 + a.bo1[128 + d], 0.f);
    __syncthreads();
    float o = 0.f;
    #pragma unroll 4
    for (int dd = 0; dd < 256; ++dd)
      o = fmaf(hh[dd], Wo2T[dd * 128 + d], o);
    a.out[bi * 128 + d] = o + a.bo2[d];
  }
}

// ---------------------------------------------------------------------------
extern "C" void kernel_launch(void* const* d_in, const int* in_sizes, int n_in,
                              void* d_out, int out_size, void* d_ws, size_t ws_size,
                              hipStream_t stream) {
  Args a;
  a.xin  = (const float*)d_in[0];  a.noise = (const float*)d_in[1];
  a.smu  = (const float*)d_in[2];  a.sls   = (const float*)d_in[3];
  a.Wq   = (const float*)d_in[4];  a.Wk    = (const float*)d_in[5];
  a.Wih  = (const float*)d_in[6];  a.Whh   = (const float*)d_in[7];
  a.bih  = (const float*)d_in[8];  a.bhh   = (const float*)d_in[9];
  a.Wm1  = (const float*)d_in[10]; a.bm1   = (const float*)d_in[11];
  a.Wm2  = (const float*)d_in[12]; a.bm2   = (const float*)d_in[13];
  a.gin  = (const float*)d_in[14]; a.bin   = (const float*)d_in[15];
  a.gsl  = (const float*)d_in[16]; a.bsl   = (const float*)d_in[17];
  a.gmu  = (const float*)d_in[18]; a.bmu   = (const float*)d_in[19];
  a.Wo1  = (const float*)d_in[20]; a.bo1   = (const float*)d_in[21];
  a.Wo2  = (const float*)d_in[22]; a.bo2   = (const float*)d_in[23];
  a.ws   = (float*)d_ws;
  a.out  = (float*)d_out;

  float* ws = (float*)d_ws;
  hipLaunchKernelGGL(init_kernel, dim3(1153), dim3(256), 0, stream,
                     a.Wq, a.Wk, a.Wih, a.Whh, a.Wm1, a.Wm2, a.Wo1, a.Wo2,
                     a.smu, a.sls, a.noise, ws);
  hipLaunchKernelGGL(ks1_kernel, dim3(640), dim3(256), 0, stream,
                     a.xin, a.gin, a.bin, ws + OFF_WKT, ws + OFF_K,
                     ws + OFF_SLOTS, a.gsl, a.bsl, ws + OFF_WQT,
                     ws + OFF_MUS, ws + OFF_WA, ws + OFF_WB, ws + OFF_CZ);
  for (int s = 0; s < 4; ++s) {
    hipLaunchKernelGGL(step_kernel, dim3(32, 16), dim3(1024), 0, stream, a, s);
  }
}